// Round 6
// baseline (681.348 us; speedup 1.0000x reference)
//
#include <hip/hip_runtime.h>
#include <cstdint>
#include <cstddef>

#define C_DIM 768
#define NPIX  1024
#define B_DIM 16
#define NTOT  16384
#define KT_N  12      // 768/64 K-tiles (K-step 64 for i8 MFMA)
#define MT_N  6       // 768/128 M-tiles
#define JT_N  128     // 16384/128 N-tiles
#define TAU   2.5e-3f
#define CAP_REC 262144
#define PLANE_B (C_DIM * C_DIM)   // bytes per i8 weight plane
#define TILE_B  8192              // bytes per 128x64 i8 tile

typedef __attribute__((ext_vector_type(4)))  int   int4v;
typedef __attribute__((ext_vector_type(16))) char  char16v;

__device__ __forceinline__ void gload16(const void* g, void* l) {
    __builtin_amdgcn_global_load_lds(
        (const __attribute__((address_space(1))) unsigned int*)g,
        (__attribute__((address_space(3))) unsigned int*)l, 16, 0, 0);
}

// ---------------------------------------------------------------------------
// Weight prep: w(f32) -> int16 fixed point (w16 = round(w*2^14), |w16|<=32639)
// -> two i8 planes hi/lo (w16 = 256*hi + lo), A-blob layout:
// plane[s][tile=kt*6+mt][kg(4)][m(128)][e(16)]  (8KB tiles, 16B chunks)
// ---------------------------------------------------------------------------
__global__ __launch_bounds__(256) void prep_weights(
    const float* __restrict__ w0, const float* __restrict__ w1,
    const float* __restrict__ w2, const float* __restrict__ w3,
    char* __restrict__ wall)
{
    const int tile = blockIdx.x;          // kt*6 + mt
    const int set  = blockIdx.y;
    const int kt = tile / MT_N, mt = tile % MT_N;
    const float* w = set == 0 ? w0 : set == 1 ? w1 : set == 2 ? w2 : w3;
    char* pl = wall + (size_t)set * 2 * PLANE_B;
#pragma unroll
    for (int i = 0; i < 2; ++i) {
        int q = threadIdx.x + i * 256;    // chunk (kg, m)
        int kg = q >> 7, m = q & 127;
        int o = mt * 128 + m;
        int cbase = kt * 64 + kg * 16;
        char16v H, L;
#pragma unroll
        for (int e = 0; e < 16; ++e) {
            float wv = w[(size_t)o * C_DIM + cbase + e];
            int w16 = (int)lrintf(wv * 16384.0f);
            w16 = w16 > 32639 ? 32639 : (w16 < -32639 ? -32639 : w16);
            int hi = (w16 + 128) >> 8;
            int lo = w16 - (hi << 8);
            H[e] = (char)hi;
            L[e] = (char)lo;
        }
        size_t base = (size_t)tile * TILE_B + (size_t)q * 16;
        *(char16v*)(pl + base)           = H;
        *(char16v*)(pl + PLANE_B + base) = L;
    }
}

// ---------------------------------------------------------------------------
// Input spikes xs = (x >= 2) as i8 {0,1}, B-blob layout:
// xs[tile=jt*12+kt][kg(4)][col(128)][e(16)]
// ---------------------------------------------------------------------------
__global__ __launch_bounds__(256) void prep_spikes(
    const float* __restrict__ x, char* __restrict__ xs)
{
    const int jt = blockIdx.x;            // 0..127
    const int kt = blockIdx.y;            // 0..11
    const int b  = jt >> 3;
    const int n0 = (jt & 7) * 128;
#pragma unroll
    for (int i = 0; i < 2; ++i) {
        int q = threadIdx.x + i * 256;    // (kg, col)
        int kg = q >> 7, col = q & 127;
        char16v sv;
#pragma unroll
        for (int e = 0; e < 16; ++e) {
            float xv = x[((size_t)b * C_DIM + (kt * 64 + kg * 16 + e)) * NPIX + n0 + col];
            sv[e] = (xv >= 2.0f) ? (char)1 : (char)0;
        }
        *(char16v*)(xs + (size_t)(jt * KT_N + kt) * TILE_B + (size_t)q * 16) = sv;
    }
}

// ---------------------------------------------------------------------------
// Branch GEMMs (q,k,v via blockIdx.z) with mfma_i32_16x16x64_i8, 2 i8 planes.
// acc exact i32; value = (256*acc_hi + acc_lo) * 2^-14 (exact float).
// Epilogue: BN + spike; |ybn-2|<TAU recorded for numpy-bit-exact pass-2.
// Output: spike B-blob i8 {0,1}.
// ---------------------------------------------------------------------------
__global__ __launch_bounds__(256) void branch_mfma(
    const char* __restrict__ wall, const char* __restrict__ xsblob,
    const float* __restrict__ qg, const float* __restrict__ qb,
    const float* __restrict__ qm, const float* __restrict__ qv,
    const float* __restrict__ kg_, const float* __restrict__ kb_,
    const float* __restrict__ km, const float* __restrict__ kvr,
    const float* __restrict__ vg, const float* __restrict__ vb,
    const float* __restrict__ vm, const float* __restrict__ vv,
    char* __restrict__ sall,
    unsigned int* __restrict__ cnt, unsigned int* __restrict__ recs)
{
    __shared__ char stage[24576];   // A_hi(8K) | A_lo(8K) | B(8K)
    const int jt = blockIdx.x, mt = blockIdx.y, z = blockIdx.z;
    const int tid = threadIdx.x;
    const int lane = tid & 63, wv_ = tid >> 6;
    const int wr = wv_ >> 1, wc = wv_ & 1;       // 2x2 waves, 64x64 each
    const int lr = lane & 15, kg = lane >> 4;
    const char* wblob = wall + (size_t)z * 2 * PLANE_B;
    char* sblob = sall + (size_t)z * C_DIM * NTOT;
    const float* gamma = z == 0 ? qg : z == 1 ? kg_ : vg;
    const float* beta  = z == 0 ? qb : z == 1 ? kb_ : vb;
    const float* mean  = z == 0 ? qm : z == 1 ? km : vm;
    const float* var   = z == 0 ? qv : z == 1 ? kvr : vv;

    int4v acch[4][4], accl[4][4];
#pragma unroll
    for (int a = 0; a < 4; ++a)
#pragma unroll
        for (int b2 = 0; b2 < 4; ++b2) {
            acch[a][b2] = (int4v){0, 0, 0, 0};
            accl[a][b2] = (int4v){0, 0, 0, 0};
        }

    for (int kt = 0; kt < KT_N; ++kt) {
        const char* Abase = wblob + (size_t)(kt * MT_N + mt) * TILE_B;
        const char* Bbase = xsblob + (size_t)(jt * KT_N + kt) * TILE_B;
#pragma unroll
        for (int i = 0; i < 6; ++i) {
            int chunk = tid + i * 256;            // 0..1535
            const char* src;
            if (chunk < 512)       src = Abase + (size_t)chunk * 16;
            else if (chunk < 1024) src = Abase + PLANE_B + (size_t)(chunk - 512) * 16;
            else                   src = Bbase + (size_t)(chunk - 1024) * 16;
            gload16(src, &stage[chunk * 16]);
        }
        __syncthreads();
        int4v bfr[4];
#pragma unroll
        for (int fn = 0; fn < 4; ++fn)
            bfr[fn] = *(const int4v*)&stage[16384 + kg * 2048 + (wc * 64 + fn * 16 + lr) * 16];
#pragma unroll
        for (int fm = 0; fm < 4; ++fm) {
            int4v ah = *(const int4v*)&stage[kg * 2048 + (wr * 64 + fm * 16 + lr) * 16];
            int4v al = *(const int4v*)&stage[8192 + kg * 2048 + (wr * 64 + fm * 16 + lr) * 16];
#pragma unroll
            for (int fn = 0; fn < 4; ++fn) {
                acch[fm][fn] = __builtin_amdgcn_mfma_i32_16x16x64_i8(ah, bfr[fn], acch[fm][fn], 0, 0, 0);
                accl[fm][fn] = __builtin_amdgcn_mfma_i32_16x16x64_i8(al, bfr[fn], accl[fm][fn], 0, 0, 0);
            }
        }
        __syncthreads();
    }

    // ---- epilogue: BN + spike + band records, via LDS u8 tile [128][132]
    unsigned char* sm = (unsigned char*)stage;
    const int rbase = (lane >> 4) * 4;
#pragma unroll
    for (int fm = 0; fm < 4; ++fm)
#pragma unroll
        for (int fn = 0; fn < 4; ++fn)
#pragma unroll
            for (int r = 0; r < 4; ++r) {
                int ml = wr * 64 + fm * 16 + rbase + r;
                int nl = wc * 64 + fn * 16 + lr;
                int o = mt * 128 + ml;
                int vi = acch[fm][fn][r] * 256 + accl[fm][fn][r];
                float y = (float)vi * 6.103515625e-05f;    // *2^-14, exact
                float invv = gamma[o] / sqrtf(var[o] + 1e-5f);
                float bias = beta[o] - mean[o] * invv;
                float ybn = y * invv + bias;
                sm[ml * 132 + nl] = (ybn >= 2.0f) ? 1 : 0;
                if (fabsf(ybn - 2.0f) < TAU) {
                    unsigned int idx = atomicAdd(cnt, 1u);
                    if (idx < CAP_REC) {
                        int j = jt * 128 + nl;
                        recs[idx] = ((unsigned)z << 24) | ((unsigned)o << 14) | (unsigned)j;
                    }
                }
            }
    __syncthreads();
    // ---- write spike blob (i8 B-operand layout): this block covers
    // downstream k-tiles kt2 = mt*2 + {0,1}
#pragma unroll
    for (int i = 0; i < 4; ++i) {
        int q = tid + i * 256;                    // (kti(2), kg2(4), col(128))
        int kti = q >> 9, rem = q & 511;
        int kg2 = rem >> 7, col = rem & 127;
        char16v vblk;
#pragma unroll
        for (int e = 0; e < 16; ++e)
            vblk[e] = sm[(kti * 64 + kg2 * 16 + e) * 132 + col] ? (char)1 : (char)0;
        *(char16v*)(sblob + (size_t)(jt * KT_N + mt * 2 + kti) * TILE_B + (size_t)rem * 16) = vblk;
    }
}

// ---------------------------------------------------------------------------
// Pass-2 fixup: bit-exact numpy fp32 recompute of borderline spikes.
// Gather from i8 xs blob; one lane does 768 serial ascending unfused adds.
// ---------------------------------------------------------------------------
__global__ __launch_bounds__(256) void fixup(
    const char* __restrict__ xs,
    const float* __restrict__ wq, const float* __restrict__ wk, const float* __restrict__ wv,
    const float* __restrict__ qg, const float* __restrict__ qb, const float* __restrict__ qm, const float* __restrict__ qv,
    const float* __restrict__ kg, const float* __restrict__ kb2, const float* __restrict__ km, const float* __restrict__ kvr,
    const float* __restrict__ vg, const float* __restrict__ vb, const float* __restrict__ vm, const float* __restrict__ vv,
    char* __restrict__ sq, char* __restrict__ sk, char* __restrict__ sv,
    const unsigned int* __restrict__ cnt, const unsigned int* __restrict__ recs)
{
#pragma clang fp contract(off)
    __shared__ float pl[C_DIM];
    unsigned int count = *cnt; if (count > CAP_REC) count = CAP_REC;
    for (unsigned int r = blockIdx.x; r < count; r += gridDim.x) {
        unsigned int rec = recs[r];
        int plane = rec >> 24, o = (rec >> 14) & 1023, j = rec & 16383;
        int jt = j >> 7, col = j & 127;
        const float* w = plane == 0 ? wq : plane == 1 ? wk : wv;
        for (int c = threadIdx.x; c < C_DIM; c += 256) {
            char s = xs[(size_t)(jt * KT_N + (c >> 6)) * TILE_B
                        + ((c >> 4) & 3) * 2048 + col * 16 + (c & 15)];
            pl[c] = s ? w[(size_t)o * C_DIM + c] : 0.0f;
        }
        __syncthreads();
        if (threadIdx.x == 0) {
            float s = 0.0f;
#pragma unroll 1
            for (int c = 0; c < C_DIM; ++c) s = s + pl[c];
            const float* g  = plane == 0 ? qg : plane == 1 ? kg : vg;
            const float* be = plane == 0 ? qb : plane == 1 ? kb2 : vb;
            const float* me = plane == 0 ? qm : plane == 1 ? km : vm;
            const float* va = plane == 0 ? qv : plane == 1 ? kvr : vv;
            float invv = g[o] / sqrtf(va[o] + 1e-5f);
            float t1 = me[o] * invv;
            float bias = be[o] - t1;
            float t3 = s * invv;
            float ybn = t3 + bias;
            char spv = (ybn >= 2.0f) ? (char)1 : (char)0;
            char* blob = plane == 0 ? sq : plane == 1 ? sk : sv;
            blob[(size_t)(jt * KT_N + (o >> 6)) * TILE_B
                 + ((o >> 4) & 3) * 2048 + col * 16 + (o & 15)] = spv;
        }
        __syncthreads();
    }
}

// ---------------------------------------------------------------------------
// maskb[b][c] = OR_n (sk & sv), bytes {0,1}
// ---------------------------------------------------------------------------
__global__ __launch_bounds__(256) void kv_mask_blob(
    const char* __restrict__ sk, const char* __restrict__ sv,
    unsigned char* __restrict__ maskb)
{
    const int kt = blockIdx.x, b = blockIdx.y;
    const int t = threadIdx.x;
    const int kg = t >> 6;
    const int col0 = (t & 63) * 2;
    __shared__ unsigned int lmask[4][4];
    if (t < 16) lmask[t >> 2][t & 3] = 0;
    __syncthreads();
    uint4 acc = make_uint4(0, 0, 0, 0);
    for (int jti = 0; jti < 8; ++jti) {
        size_t base = (size_t)((b * 8 + jti) * KT_N + kt) * TILE_B + kg * 2048;
#pragma unroll
        for (int cc = 0; cc < 2; ++cc) {
            uint4 kk = *(const uint4*)(sk + base + (size_t)(col0 + cc) * 16);
            uint4 vv = *(const uint4*)(sv + base + (size_t)(col0 + cc) * 16);
            acc.x |= (kk.x & vv.x); acc.y |= (kk.y & vv.y);
            acc.z |= (kk.z & vv.z); acc.w |= (kk.w & vv.w);
        }
    }
    if (acc.x) atomicOr(&lmask[kg][0], acc.x);
    if (acc.y) atomicOr(&lmask[kg][1], acc.y);
    if (acc.z) atomicOr(&lmask[kg][2], acc.z);
    if (acc.w) atomicOr(&lmask[kg][3], acc.w);
    __syncthreads();
    if (t < 64) {
        int kg2 = t >> 4, e = t & 15;
        unsigned int dw = lmask[kg2][e >> 2];
        unsigned char byte = (dw >> ((e & 3) * 8)) & 0xFF;
        maskb[(size_t)b * C_DIM + kt * 64 + t] = byte ? 1 : 0;
    }
}

// ---------------------------------------------------------------------------
// Final projection: out = (wp·(sq & mask) + bp)*inv + bias + x
// mask ANDed into B fragments in registers (staged to LDS once).
// ---------------------------------------------------------------------------
__global__ __launch_bounds__(256) void final_mfma(
    const char* __restrict__ wblob, const char* __restrict__ sqblob,
    const unsigned char* __restrict__ maskb,
    const float* __restrict__ x, const float* __restrict__ bp,
    const float* __restrict__ gamma, const float* __restrict__ beta,
    const float* __restrict__ mean, const float* __restrict__ var,
    float* __restrict__ out)
{
    __shared__ char stage[24576];
    __shared__ char mlds[768];
    const int jt = blockIdx.x, mt = blockIdx.y;
    const int tid = threadIdx.x;
    const int lane = tid & 63, wv_ = tid >> 6;
    const int wr = wv_ >> 1, wc = wv_ & 1;
    const int lr = lane & 15, kg = lane >> 4;
    const int b = jt >> 3;

    if (tid < 48)
        *(int4v*)&mlds[tid * 16] = *(const int4v*)(maskb + (size_t)b * C_DIM + tid * 16);

    int4v acch[4][4], accl[4][4];
#pragma unroll
    for (int a = 0; a < 4; ++a)
#pragma unroll
        for (int b2 = 0; b2 < 4; ++b2) {
            acch[a][b2] = (int4v){0, 0, 0, 0};
            accl[a][b2] = (int4v){0, 0, 0, 0};
        }

    for (int kt = 0; kt < KT_N; ++kt) {
        const char* Abase = wblob + (size_t)(kt * MT_N + mt) * TILE_B;
        const char* Bbase = sqblob + (size_t)(jt * KT_N + kt) * TILE_B;
#pragma unroll
        for (int i = 0; i < 6; ++i) {
            int chunk = tid + i * 256;
            const char* src;
            if (chunk < 512)       src = Abase + (size_t)chunk * 16;
            else if (chunk < 1024) src = Abase + PLANE_B + (size_t)(chunk - 512) * 16;
            else                   src = Bbase + (size_t)(chunk - 1024) * 16;
            gload16(src, &stage[chunk * 16]);
        }
        __syncthreads();
        int4v mp = *(const int4v*)&mlds[kt * 64 + kg * 16];
        int4v bfr[4];
#pragma unroll
        for (int fn = 0; fn < 4; ++fn) {
            bfr[fn] = *(const int4v*)&stage[16384 + kg * 2048 + (wc * 64 + fn * 16 + lr) * 16];
            bfr[fn] &= mp;
        }
#pragma unroll
        for (int fm = 0; fm < 4; ++fm) {
            int4v ah = *(const int4v*)&stage[kg * 2048 + (wr * 64 + fm * 16 + lr) * 16];
            int4v al = *(const int4v*)&stage[8192 + kg * 2048 + (wr * 64 + fm * 16 + lr) * 16];
#pragma unroll
            for (int fn = 0; fn < 4; ++fn) {
                acch[fm][fn] = __builtin_amdgcn_mfma_i32_16x16x64_i8(ah, bfr[fn], acch[fm][fn], 0, 0, 0);
                accl[fm][fn] = __builtin_amdgcn_mfma_i32_16x16x64_i8(al, bfr[fn], accl[fm][fn], 0, 0, 0);
            }
        }
        __syncthreads();
    }

    const int n0 = (jt & 7) * 128;
    const int rbase = (lane >> 4) * 4;
#pragma unroll
    for (int fm = 0; fm < 4; ++fm)
#pragma unroll
        for (int fn = 0; fn < 4; ++fn)
#pragma unroll
            for (int r = 0; r < 4; ++r) {
                int ml = wr * 64 + fm * 16 + rbase + r;
                int nl = wc * 64 + fn * 16 + lr;
                int p = mt * 128 + ml;
                int vi = acch[fm][fn][r] * 256 + accl[fm][fn][r];
                float pre = (float)vi * 6.103515625e-05f;
                float invv = gamma[p] / sqrtf(var[p] + 1e-5f);
                float bias = beta[p] - mean[p] * invv;
                size_t idx = ((size_t)b * C_DIM + p) * NPIX + n0 + nl;
                out[idx] = (pre + bp[p]) * invv + bias + x[idx];
            }
}

extern "C" void kernel_launch(void* const* d_in, const int* in_sizes, int n_in,
                              void* d_out, int out_size, void* d_ws, size_t ws_size,
                              hipStream_t stream) {
    const float* x  = (const float*)d_in[0];
    const float* wq = (const float*)d_in[1];
    const float* qg = (const float*)d_in[2];
    const float* qb = (const float*)d_in[3];
    const float* qm = (const float*)d_in[4];
    const float* qv = (const float*)d_in[5];
    const float* wk = (const float*)d_in[6];
    const float* kg = (const float*)d_in[7];
    const float* kb = (const float*)d_in[8];
    const float* km = (const float*)d_in[9];
    const float* kvv= (const float*)d_in[10];
    const float* wv = (const float*)d_in[11];
    const float* vg = (const float*)d_in[12];
    const float* vb = (const float*)d_in[13];
    const float* vm = (const float*)d_in[14];
    const float* vv = (const float*)d_in[15];
    const float* wp = (const float*)d_in[16];
    const float* bp = (const float*)d_in[17];
    const float* pg = (const float*)d_in[18];
    const float* pb = (const float*)d_in[19];
    const float* pm = (const float*)d_in[20];
    const float* pv = (const float*)d_in[21];

    const size_t SPIKE = (size_t)C_DIM * NTOT;       // bytes per spike blob
    char* sq  = (char*)d_ws;
    char* sk  = sq + SPIKE;
    char* sv  = sk + SPIKE;
    char* xs  = sv + SPIKE;
    char* wall = xs + SPIKE;                         // 4 sets x 2 planes
    unsigned char* maskb = (unsigned char*)(wall + (size_t)4 * 2 * PLANE_B);
    unsigned int* cnt  = (unsigned int*)(maskb + 16384);
    unsigned int* recs = (unsigned int*)((char*)cnt + 256);
    char* wpb = wall + (size_t)3 * 2 * PLANE_B;

    hipMemsetAsync(cnt, 0, 4, stream);
    prep_weights<<<dim3(KT_N * MT_N, 4), 256, 0, stream>>>(wq, wk, wv, wp, wall);
    prep_spikes<<<dim3(JT_N, KT_N), 256, 0, stream>>>(x, xs);
    branch_mfma<<<dim3(JT_N, MT_N, 3), 256, 0, stream>>>(
        wall, xs, qg, qb, qm, qv, kg, kb, km, kvv, vg, vb, vm, vv, sq, cnt, recs);
    fixup<<<8192, 256, 0, stream>>>(xs, wq, wk, wv,
                                    qg, qb, qm, qv, kg, kb, km, kvv, vg, vb, vm, vv,
                                    sq, sk, sv, cnt, recs);
    kv_mask_blob<<<dim3(KT_N, B_DIM), 256, 0, stream>>>(sk, sv, maskb);
    final_mfma<<<dim3(JT_N, MT_N), 256, 0, stream>>>(
        wpb, sq, maskb, x, bp, pg, pb, pm, pv, (float*)d_out);
}

// Round 7
// 309.533 us; speedup vs baseline: 2.2012x; 2.2012x over previous
//
#include <hip/hip_runtime.h>
#include <cstdint>
#include <cstddef>

#define C_DIM 768
#define NPIX  1024
#define B_DIM 16
#define NTOT  16384
#define KT_N  12      // 768/64 K-tiles (K-step 64 for i8 MFMA)
#define MT_N  6       // 768/128 M-tiles
#define JT_N  128     // 16384/128 N-tiles
#define TAU   2.0e-3f
#define CAP_REC 262144
#define PLANE_B (C_DIM * C_DIM)   // bytes per i8 weight plane
#define TILE_B  8192              // bytes per 128x64 i8 tile

typedef __attribute__((ext_vector_type(4)))  int   int4v;
typedef __attribute__((ext_vector_type(16))) char  char16v;

__device__ __forceinline__ void gload16(const void* g, void* l) {
    __builtin_amdgcn_global_load_lds(
        (const __attribute__((address_space(1))) unsigned int*)g,
        (__attribute__((address_space(3))) unsigned int*)l, 16, 0, 0);
}

// ---------------------------------------------------------------------------
// Weight prep: w(f32) -> int16 fixed point (w16 = round(w*2^14), |w16|<=32639)
// -> two i8 planes hi/lo (w16 = 256*hi + lo), A-blob layout:
// plane[s][tile=kt*6+mt][kg(4)][m(128)][e(16)]  (8KB tiles, 16B chunks)
// ---------------------------------------------------------------------------
__global__ __launch_bounds__(256) void prep_weights(
    const float* __restrict__ w0, const float* __restrict__ w1,
    const float* __restrict__ w2, const float* __restrict__ w3,
    char* __restrict__ wall)
{
    const int tile = blockIdx.x;          // kt*6 + mt
    const int set  = blockIdx.y;
    const int kt = tile / MT_N, mt = tile % MT_N;
    const float* w = set == 0 ? w0 : set == 1 ? w1 : set == 2 ? w2 : w3;
    char* pl = wall + (size_t)set * 2 * PLANE_B;
#pragma unroll
    for (int i = 0; i < 2; ++i) {
        int q = threadIdx.x + i * 256;    // chunk (kg, m)
        int kg = q >> 7, m = q & 127;
        int o = mt * 128 + m;
        int cbase = kt * 64 + kg * 16;
        char16v H, L;
#pragma unroll
        for (int e = 0; e < 16; ++e) {
            float wv = w[(size_t)o * C_DIM + cbase + e];
            int w16 = (int)lrintf(wv * 16384.0f);
            w16 = w16 > 32639 ? 32639 : (w16 < -32639 ? -32639 : w16);
            int hi = (w16 + 128) >> 8;
            int lo = w16 - (hi << 8);
            H[e] = (char)hi;
            L[e] = (char)lo;
        }
        size_t base = (size_t)tile * TILE_B + (size_t)q * 16;
        *(char16v*)(pl + base)           = H;
        *(char16v*)(pl + PLANE_B + base) = L;
    }
}

// ---------------------------------------------------------------------------
// Input spikes xs = (x >= 2) as i8 {0,1}, B-blob layout:
// xs[tile=jt*12+kt][kg(4)][col(128)][e(16)]
// ---------------------------------------------------------------------------
__global__ __launch_bounds__(256) void prep_spikes(
    const float* __restrict__ x, char* __restrict__ xs)
{
    const int jt = blockIdx.x;            // 0..127
    const int kt = blockIdx.y;            // 0..11
    const int b  = jt >> 3;
    const int n0 = (jt & 7) * 128;
#pragma unroll
    for (int i = 0; i < 2; ++i) {
        int q = threadIdx.x + i * 256;    // (kg, col)
        int kg = q >> 7, col = q & 127;
        char16v sv;
#pragma unroll
        for (int e = 0; e < 16; ++e) {
            float xv = x[((size_t)b * C_DIM + (kt * 64 + kg * 16 + e)) * NPIX + n0 + col];
            sv[e] = (xv >= 2.0f) ? (char)1 : (char)0;
        }
        *(char16v*)(xs + (size_t)(jt * KT_N + kt) * TILE_B + (size_t)q * 16) = sv;
    }
}

// ---------------------------------------------------------------------------
// Branch GEMMs (q,k,v via blockIdx.z) with mfma_i32_16x16x64_i8, 2 i8 planes.
// acc exact i32; value = (256*acc_hi + acc_lo) * 2^-14 (exact float).
// Epilogue: BN + spike; |ybn-2|<TAU recorded for numpy-bit-exact pass-2.
// Output: spike B-blob i8 {0,1}.
// ---------------------------------------------------------------------------
__global__ __launch_bounds__(256) void branch_mfma(
    const char* __restrict__ wall, const char* __restrict__ xsblob,
    const float* __restrict__ qg, const float* __restrict__ qb,
    const float* __restrict__ qm, const float* __restrict__ qv,
    const float* __restrict__ kg_, const float* __restrict__ kb_,
    const float* __restrict__ km, const float* __restrict__ kvr,
    const float* __restrict__ vg, const float* __restrict__ vb,
    const float* __restrict__ vm, const float* __restrict__ vv,
    char* __restrict__ sall,
    unsigned int* __restrict__ cnt, unsigned int* __restrict__ recs)
{
    __shared__ char stage[24576];   // A_hi(8K) | A_lo(8K) | B(8K)
    const int jt = blockIdx.x, mt = blockIdx.y, z = blockIdx.z;
    const int tid = threadIdx.x;
    const int lane = tid & 63, wv_ = tid >> 6;
    const int wr = wv_ >> 1, wc = wv_ & 1;       // 2x2 waves, 64x64 each
    const int lr = lane & 15, kg = lane >> 4;
    const char* wblob = wall + (size_t)z * 2 * PLANE_B;
    char* sblob = sall + (size_t)z * C_DIM * NTOT;
    const float* gamma = z == 0 ? qg : z == 1 ? kg_ : vg;
    const float* beta  = z == 0 ? qb : z == 1 ? kb_ : vb;
    const float* mean  = z == 0 ? qm : z == 1 ? km : vm;
    const float* var   = z == 0 ? qv : z == 1 ? kvr : vv;

    int4v acch[4][4], accl[4][4];
#pragma unroll
    for (int a = 0; a < 4; ++a)
#pragma unroll
        for (int b2 = 0; b2 < 4; ++b2) {
            acch[a][b2] = (int4v){0, 0, 0, 0};
            accl[a][b2] = (int4v){0, 0, 0, 0};
        }

    for (int kt = 0; kt < KT_N; ++kt) {
        const char* Abase = wblob + (size_t)(kt * MT_N + mt) * TILE_B;
        const char* Bbase = xsblob + (size_t)(jt * KT_N + kt) * TILE_B;
#pragma unroll
        for (int i = 0; i < 6; ++i) {
            int chunk = tid + i * 256;            // 0..1535
            const char* src;
            if (chunk < 512)       src = Abase + (size_t)chunk * 16;
            else if (chunk < 1024) src = Abase + PLANE_B + (size_t)(chunk - 512) * 16;
            else                   src = Bbase + (size_t)(chunk - 1024) * 16;
            gload16(src, &stage[chunk * 16]);
        }
        __syncthreads();
        int4v bfr[4];
#pragma unroll
        for (int fn = 0; fn < 4; ++fn)
            bfr[fn] = *(const int4v*)&stage[16384 + kg * 2048 + (wc * 64 + fn * 16 + lr) * 16];
#pragma unroll
        for (int fm = 0; fm < 4; ++fm) {
            int4v ah = *(const int4v*)&stage[kg * 2048 + (wr * 64 + fm * 16 + lr) * 16];
            int4v al = *(const int4v*)&stage[8192 + kg * 2048 + (wr * 64 + fm * 16 + lr) * 16];
#pragma unroll
            for (int fn = 0; fn < 4; ++fn) {
                acch[fm][fn] = __builtin_amdgcn_mfma_i32_16x16x64_i8(ah, bfr[fn], acch[fm][fn], 0, 0, 0);
                accl[fm][fn] = __builtin_amdgcn_mfma_i32_16x16x64_i8(al, bfr[fn], accl[fm][fn], 0, 0, 0);
            }
        }
        __syncthreads();
    }

    // ---- epilogue: BN + spike + band records, via LDS u8 tile [128][132]
    unsigned char* sm = (unsigned char*)stage;
    const int rbase = (lane >> 4) * 4;
#pragma unroll
    for (int fm = 0; fm < 4; ++fm)
#pragma unroll
        for (int fn = 0; fn < 4; ++fn)
#pragma unroll
            for (int r = 0; r < 4; ++r) {
                int ml = wr * 64 + fm * 16 + rbase + r;
                int nl = wc * 64 + fn * 16 + lr;
                int o = mt * 128 + ml;
                int vi = acch[fm][fn][r] * 256 + accl[fm][fn][r];
                float y = (float)vi * 6.103515625e-05f;    // *2^-14, exact
                float invv = gamma[o] / sqrtf(var[o] + 1e-5f);
                float bias = beta[o] - mean[o] * invv;
                float ybn = y * invv + bias;
                sm[ml * 132 + nl] = (ybn >= 2.0f) ? 1 : 0;
                if (fabsf(ybn - 2.0f) < TAU) {
                    unsigned int idx = atomicAdd(cnt, 1u);
                    if (idx < CAP_REC) {
                        int j = jt * 128 + nl;
                        recs[idx] = ((unsigned)z << 24) | ((unsigned)o << 14) | (unsigned)j;
                    }
                }
            }
    __syncthreads();
    // ---- write spike blob (i8 B-operand layout): this block covers
    // downstream k-tiles kt2 = mt*2 + {0,1}
#pragma unroll
    for (int i = 0; i < 4; ++i) {
        int q = tid + i * 256;                    // (kti(2), kg2(4), col(128))
        int kti = q >> 9, rem = q & 511;
        int kg2 = rem >> 7, col = rem & 127;
        char16v vblk;
#pragma unroll
        for (int e = 0; e < 16; ++e)
            vblk[e] = sm[(kti * 64 + kg2 * 16 + e) * 132 + col] ? (char)1 : (char)0;
        *(char16v*)(sblob + (size_t)(jt * KT_N + mt * 2 + kti) * TILE_B + (size_t)rem * 16) = vblk;
    }
}

// ---------------------------------------------------------------------------
// Pass-2 fixup, wave-per-record: bit-exact numpy fp32 re-resolution.
// numpy chain s += p_c with p_c==0 leaves s bit-identical -> only active-spike
// weights matter. 64 lanes do an ordered ballot-compaction of active weights
// (ascending c preserved) into LDS; lane 0 runs the short serial chain
// (compiler batches the ds_reads; adds stay strictly ordered/unfused).
// ---------------------------------------------------------------------------
__global__ __launch_bounds__(256) void fixup(
    const char* __restrict__ xs,
    const float* __restrict__ wq, const float* __restrict__ wk, const float* __restrict__ wv,
    const float* __restrict__ qg, const float* __restrict__ qb, const float* __restrict__ qm, const float* __restrict__ qv,
    const float* __restrict__ kg, const float* __restrict__ kb2, const float* __restrict__ km, const float* __restrict__ kvr,
    const float* __restrict__ vg, const float* __restrict__ vb, const float* __restrict__ vm, const float* __restrict__ vv,
    char* __restrict__ sq, char* __restrict__ sk, char* __restrict__ sv,
    const unsigned int* __restrict__ cnt, const unsigned int* __restrict__ recs)
{
#pragma clang fp contract(off)
    __shared__ float cw[4][C_DIM];
    const int lane = threadIdx.x & 63;
    const int wvid = threadIdx.x >> 6;
    const int gwave = blockIdx.x * 4 + wvid;
    const int nwaves = gridDim.x * 4;
    unsigned int count = *cnt; if (count > CAP_REC) count = CAP_REC;

    for (unsigned int r = gwave; r < count; r += nwaves) {
        unsigned int rec = recs[r];
        int plane = rec >> 24, o = (rec >> 14) & 1023, j = rec & 16383;
        int jt = j >> 7, col = j & 127;
        const float* w = plane == 0 ? wq : plane == 1 ? wk : wv;
        int base = 0;
#pragma unroll
        for (int cc = 0; cc < 12; ++cc) {
            int c = cc * 64 + lane;
            char s = xs[(size_t)(jt * KT_N + (c >> 6)) * TILE_B
                        + ((c >> 4) & 3) * 2048 + col * 16 + (c & 15)];
            float wvv = w[(size_t)o * C_DIM + c];
            bool act = (s != 0);
            unsigned long long m = __ballot(act);
            int pos = __popcll(m & ((1ull << lane) - 1ull));
            if (act) cw[wvid][base + pos] = wvv;
            base += __popcll(m);
        }
        // wave-coherent LDS: lane 0 consumes after all lanes' writes complete
        __builtin_amdgcn_s_waitcnt(0);       // lgkmcnt(0)+vmcnt(0)
        if (lane == 0) {
            float s = 0.0f;
            for (int i = 0; i < base; ++i) s = s + cw[wvid][i];   // strict order
            const float* g  = plane == 0 ? qg : plane == 1 ? kg : vg;
            const float* be = plane == 0 ? qb : plane == 1 ? kb2 : vb;
            const float* me = plane == 0 ? qm : plane == 1 ? km : vm;
            const float* va = plane == 0 ? qv : plane == 1 ? kvr : vv;
            float invv = g[o] / sqrtf(va[o] + 1e-5f);
            float t1 = me[o] * invv;
            float bias = be[o] - t1;
            float t3 = s * invv;
            float ybn = t3 + bias;
            char spv = (ybn >= 2.0f) ? (char)1 : (char)0;
            char* blob = plane == 0 ? sq : plane == 1 ? sk : sv;
            blob[(size_t)(jt * KT_N + (o >> 6)) * TILE_B
                 + ((o >> 4) & 3) * 2048 + col * 16 + (o & 15)] = spv;
        }
    }
}

// ---------------------------------------------------------------------------
// maskb[b][c] = OR_n (sk & sv), bytes {0,1}
// ---------------------------------------------------------------------------
__global__ __launch_bounds__(256) void kv_mask_blob(
    const char* __restrict__ sk, const char* __restrict__ sv,
    unsigned char* __restrict__ maskb)
{
    const int kt = blockIdx.x, b = blockIdx.y;
    const int t = threadIdx.x;
    const int kg = t >> 6;
    const int col0 = (t & 63) * 2;
    __shared__ unsigned int lmask[4][4];
    if (t < 16) lmask[t >> 2][t & 3] = 0;
    __syncthreads();
    uint4 acc = make_uint4(0, 0, 0, 0);
    for (int jti = 0; jti < 8; ++jti) {
        size_t base = (size_t)((b * 8 + jti) * KT_N + kt) * TILE_B + kg * 2048;
#pragma unroll
        for (int cc = 0; cc < 2; ++cc) {
            uint4 kk = *(const uint4*)(sk + base + (size_t)(col0 + cc) * 16);
            uint4 vv = *(const uint4*)(sv + base + (size_t)(col0 + cc) * 16);
            acc.x |= (kk.x & vv.x); acc.y |= (kk.y & vv.y);
            acc.z |= (kk.z & vv.z); acc.w |= (kk.w & vv.w);
        }
    }
    if (acc.x) atomicOr(&lmask[kg][0], acc.x);
    if (acc.y) atomicOr(&lmask[kg][1], acc.y);
    if (acc.z) atomicOr(&lmask[kg][2], acc.z);
    if (acc.w) atomicOr(&lmask[kg][3], acc.w);
    __syncthreads();
    if (t < 64) {
        int kg2 = t >> 4, e = t & 15;
        unsigned int dw = lmask[kg2][e >> 2];
        unsigned char byte = (dw >> ((e & 3) * 8)) & 0xFF;
        maskb[(size_t)b * C_DIM + kt * 64 + t] = byte ? 1 : 0;
    }
}

// ---------------------------------------------------------------------------
// Final projection: out = (wp·(sq & mask) + bp)*inv + bias + x
// mask ANDed into B fragments in registers (staged to LDS once).
// ---------------------------------------------------------------------------
__global__ __launch_bounds__(256) void final_mfma(
    const char* __restrict__ wblob, const char* __restrict__ sqblob,
    const unsigned char* __restrict__ maskb,
    const float* __restrict__ x, const float* __restrict__ bp,
    const float* __restrict__ gamma, const float* __restrict__ beta,
    const float* __restrict__ mean, const float* __restrict__ var,
    float* __restrict__ out)
{
    __shared__ char stage[24576];
    __shared__ char mlds[768];
    const int jt = blockIdx.x, mt = blockIdx.y;
    const int tid = threadIdx.x;
    const int lane = tid & 63, wv_ = tid >> 6;
    const int wr = wv_ >> 1, wc = wv_ & 1;
    const int lr = lane & 15, kg = lane >> 4;
    const int b = jt >> 3;

    if (tid < 48)
        *(int4v*)&mlds[tid * 16] = *(const int4v*)(maskb + (size_t)b * C_DIM + tid * 16);

    int4v acch[4][4], accl[4][4];
#pragma unroll
    for (int a = 0; a < 4; ++a)
#pragma unroll
        for (int b2 = 0; b2 < 4; ++b2) {
            acch[a][b2] = (int4v){0, 0, 0, 0};
            accl[a][b2] = (int4v){0, 0, 0, 0};
        }

    for (int kt = 0; kt < KT_N; ++kt) {
        const char* Abase = wblob + (size_t)(kt * MT_N + mt) * TILE_B;
        const char* Bbase = sqblob + (size_t)(jt * KT_N + kt) * TILE_B;
#pragma unroll
        for (int i = 0; i < 6; ++i) {
            int chunk = tid + i * 256;
            const char* src;
            if (chunk < 512)       src = Abase + (size_t)chunk * 16;
            else if (chunk < 1024) src = Abase + PLANE_B + (size_t)(chunk - 512) * 16;
            else                   src = Bbase + (size_t)(chunk - 1024) * 16;
            gload16(src, &stage[chunk * 16]);
        }
        __syncthreads();
        int4v mp = *(const int4v*)&mlds[kt * 64 + kg * 16];
        int4v bfr[4];
#pragma unroll
        for (int fn = 0; fn < 4; ++fn) {
            bfr[fn] = *(const int4v*)&stage[16384 + kg * 2048 + (wc * 64 + fn * 16 + lr) * 16];
            bfr[fn] &= mp;
        }
#pragma unroll
        for (int fm = 0; fm < 4; ++fm) {
            int4v ah = *(const int4v*)&stage[kg * 2048 + (wr * 64 + fm * 16 + lr) * 16];
            int4v al = *(const int4v*)&stage[8192 + kg * 2048 + (wr * 64 + fm * 16 + lr) * 16];
#pragma unroll
            for (int fn = 0; fn < 4; ++fn) {
                acch[fm][fn] = __builtin_amdgcn_mfma_i32_16x16x64_i8(ah, bfr[fn], acch[fm][fn], 0, 0, 0);
                accl[fm][fn] = __builtin_amdgcn_mfma_i32_16x16x64_i8(al, bfr[fn], accl[fm][fn], 0, 0, 0);
            }
        }
        __syncthreads();
    }

    const int n0 = (jt & 7) * 128;
    const int rbase = (lane >> 4) * 4;
#pragma unroll
    for (int fm = 0; fm < 4; ++fm)
#pragma unroll
        for (int fn = 0; fn < 4; ++fn)
#pragma unroll
            for (int r = 0; r < 4; ++r) {
                int ml = wr * 64 + fm * 16 + rbase + r;
                int nl = wc * 64 + fn * 16 + lr;
                int p = mt * 128 + ml;
                int vi = acch[fm][fn][r] * 256 + accl[fm][fn][r];
                float pre = (float)vi * 6.103515625e-05f;
                float invv = gamma[p] / sqrtf(var[p] + 1e-5f);
                float bias = beta[p] - mean[p] * invv;
                size_t idx = ((size_t)b * C_DIM + p) * NPIX + n0 + nl;
                out[idx] = (pre + bp[p]) * invv + bias + x[idx];
            }
}

extern "C" void kernel_launch(void* const* d_in, const int* in_sizes, int n_in,
                              void* d_out, int out_size, void* d_ws, size_t ws_size,
                              hipStream_t stream) {
    const float* x  = (const float*)d_in[0];
    const float* wq = (const float*)d_in[1];
    const float* qg = (const float*)d_in[2];
    const float* qb = (const float*)d_in[3];
    const float* qm = (const float*)d_in[4];
    const float* qv = (const float*)d_in[5];
    const float* wk = (const float*)d_in[6];
    const float* kg = (const float*)d_in[7];
    const float* kb = (const float*)d_in[8];
    const float* km = (const float*)d_in[9];
    const float* kvv= (const float*)d_in[10];
    const float* wv = (const float*)d_in[11];
    const float* vg = (const float*)d_in[12];
    const float* vb = (const float*)d_in[13];
    const float* vm = (const float*)d_in[14];
    const float* vv = (const float*)d_in[15];
    const float* wp = (const float*)d_in[16];
    const float* bp = (const float*)d_in[17];
    const float* pg = (const float*)d_in[18];
    const float* pb = (const float*)d_in[19];
    const float* pm = (const float*)d_in[20];
    const float* pv = (const float*)d_in[21];

    const size_t SPIKE = (size_t)C_DIM * NTOT;       // bytes per spike blob
    char* sq  = (char*)d_ws;
    char* sk  = sq + SPIKE;
    char* sv  = sk + SPIKE;
    char* xs  = sv + SPIKE;
    char* wall = xs + SPIKE;                         // 4 sets x 2 planes
    unsigned char* maskb = (unsigned char*)(wall + (size_t)4 * 2 * PLANE_B);
    unsigned int* cnt  = (unsigned int*)(maskb + 16384);
    unsigned int* recs = (unsigned int*)((char*)cnt + 256);
    char* wpb = wall + (size_t)3 * 2 * PLANE_B;

    hipMemsetAsync(cnt, 0, 4, stream);
    prep_weights<<<dim3(KT_N * MT_N, 4), 256, 0, stream>>>(wq, wk, wv, wp, wall);
    prep_spikes<<<dim3(JT_N, KT_N), 256, 0, stream>>>(x, xs);
    branch_mfma<<<dim3(JT_N, MT_N, 3), 256, 0, stream>>>(
        wall, xs, qg, qb, qm, qv, kg, kb, km, kvv, vg, vb, vm, vv, sq, cnt, recs);
    fixup<<<2048, 256, 0, stream>>>(xs, wq, wk, wv,
                                    qg, qb, qm, qv, kg, kb, km, kvv, vg, vb, vm, vv,
                                    sq, sk, sv, cnt, recs);
    kv_mask_blob<<<dim3(KT_N, B_DIM), 256, 0, stream>>>(sk, sv, maskb);
    final_mfma<<<dim3(JT_N, MT_N), 256, 0, stream>>>(
        wpb, sq, maskb, x, bp, pg, pb, pm, pv, (float*)d_out);
}

// Round 8
// 269.170 us; speedup vs baseline: 2.5313x; 1.1500x over previous
//
#include <hip/hip_runtime.h>
#include <cstdint>
#include <cstddef>

#define C_DIM 768
#define NPIX  1024
#define B_DIM 16
#define NTOT  16384
#define KT_N  12      // 768/64 K-tiles (K-step 64 for i8 MFMA)
#define MT_N  6       // 768/128 M-tiles
#define JT_N  128     // 16384/128 N-tiles
#define TAU   2.0e-3f
#define CAP_REC 262144
#define PLANE_B (C_DIM * C_DIM)   // bytes per i8 weight plane
#define TILE_B  8192              // bytes per 128x64 i8 tile

typedef __attribute__((ext_vector_type(4)))  int   int4v;
typedef __attribute__((ext_vector_type(16))) char  char16v;

__device__ __forceinline__ void gload16(const void* g, void* l) {
    __builtin_amdgcn_global_load_lds(
        (const __attribute__((address_space(1))) unsigned int*)g,
        (__attribute__((address_space(3))) unsigned int*)l, 16, 0, 0);
}

// ---------------------------------------------------------------------------
// Weight prep: w(f32) -> int16 fixed point (w16 = round(w*2^14), |w16|<=32639)
// -> two i8 planes hi/lo (w16 = 256*hi + lo), A-blob layout:
// plane[s][tile=kt*6+mt][kg(4)][m(128)][e(16)]  (8KB tiles, 16B chunks)
// ---------------------------------------------------------------------------
__global__ __launch_bounds__(256) void prep_weights(
    const float* __restrict__ w0, const float* __restrict__ w1,
    const float* __restrict__ w2, const float* __restrict__ w3,
    char* __restrict__ wall)
{
    const int tile = blockIdx.x;          // kt*6 + mt
    const int set  = blockIdx.y;
    const int kt = tile / MT_N, mt = tile % MT_N;
    const float* w = set == 0 ? w0 : set == 1 ? w1 : set == 2 ? w2 : w3;
    char* pl = wall + (size_t)set * 2 * PLANE_B;
#pragma unroll
    for (int i = 0; i < 2; ++i) {
        int q = threadIdx.x + i * 256;    // chunk (kg, m)
        int kg = q >> 7, m = q & 127;
        int o = mt * 128 + m;
        int cbase = kt * 64 + kg * 16;
        char16v H, L;
#pragma unroll
        for (int e = 0; e < 16; ++e) {
            float wv = w[(size_t)o * C_DIM + cbase + e];
            int w16 = (int)lrintf(wv * 16384.0f);
            w16 = w16 > 32639 ? 32639 : (w16 < -32639 ? -32639 : w16);
            int hi = (w16 + 128) >> 8;
            int lo = w16 - (hi << 8);
            H[e] = (char)hi;
            L[e] = (char)lo;
        }
        size_t base = (size_t)tile * TILE_B + (size_t)q * 16;
        *(char16v*)(pl + base)           = H;
        *(char16v*)(pl + PLANE_B + base) = L;
    }
}

// ---------------------------------------------------------------------------
// BN affine precompute: inv = g/sqrtf(v+1e-5f), bias = b - m*inv, 4 sets
// ---------------------------------------------------------------------------
__global__ __launch_bounds__(256) void prep_bn(
    const float* __restrict__ qg, const float* __restrict__ qb,
    const float* __restrict__ qm, const float* __restrict__ qv,
    const float* __restrict__ kg, const float* __restrict__ kb,
    const float* __restrict__ km, const float* __restrict__ kv,
    const float* __restrict__ vg, const float* __restrict__ vb,
    const float* __restrict__ vm, const float* __restrict__ vv,
    const float* __restrict__ pg, const float* __restrict__ pb,
    const float* __restrict__ pm, const float* __restrict__ pv,
    float* __restrict__ invt, float* __restrict__ biast)
{
    int i = blockIdx.x * 256 + threadIdx.x;     // 0..3071
    if (i >= 4 * C_DIM) return;
    int set = i / C_DIM, o = i - set * C_DIM;
    const float* g = set == 0 ? qg : set == 1 ? kg : set == 2 ? vg : pg;
    const float* b = set == 0 ? qb : set == 1 ? kb : set == 2 ? vb : pb;
    const float* m = set == 0 ? qm : set == 1 ? km : set == 2 ? vm : pm;
    const float* v = set == 0 ? qv : set == 1 ? kv : set == 2 ? vv : pv;
    float inv = g[o] / sqrtf(v[o] + 1e-5f);
    invt[i]  = inv;
    biast[i] = b[o] - m[o] * inv;
}

// ---------------------------------------------------------------------------
// Input spikes xs = (x >= 2) as i8 {0,1}, B-blob layout:
// xs[tile=jt*12+kt][kg(4)][col(128)][e(16)]
// ---------------------------------------------------------------------------
__global__ __launch_bounds__(256) void prep_spikes(
    const float* __restrict__ x, char* __restrict__ xs)
{
    const int jt = blockIdx.x;            // 0..127
    const int kt = blockIdx.y;            // 0..11
    const int b  = jt >> 3;
    const int n0 = (jt & 7) * 128;
#pragma unroll
    for (int i = 0; i < 2; ++i) {
        int q = threadIdx.x + i * 256;    // (kg, col)
        int kg = q >> 7, col = q & 127;
        char16v sv;
#pragma unroll
        for (int e = 0; e < 16; ++e) {
            float xv = x[((size_t)b * C_DIM + (kt * 64 + kg * 16 + e)) * NPIX + n0 + col];
            sv[e] = (xv >= 2.0f) ? (char)1 : (char)0;
        }
        *(char16v*)(xs + (size_t)(jt * KT_N + kt) * TILE_B + (size_t)q * 16) = sv;
    }
}

// ---------------------------------------------------------------------------
// Branch GEMMs (q,k,v via blockIdx.z), mfma_i32_16x16x64_i8, 2 i8 planes,
// 512 threads (2x4 waves, 64x32/wave), double-buffered LDS 2-phase pipeline.
// Epilogue: BN + spike; |ybn-2|<TAU recorded for numpy-bit-exact pass-2.
// ---------------------------------------------------------------------------
__global__ __launch_bounds__(512, 4) void branch_mfma(
    const char* __restrict__ wall, const char* __restrict__ xsblob,
    const float* __restrict__ invt, const float* __restrict__ biast,
    char* __restrict__ sall,
    unsigned int* __restrict__ cnt, unsigned int* __restrict__ recs)
{
    __shared__ char stage[2][24576];   // per buf: A_hi(8K) | A_lo(8K) | B(8K)
    const int jt = blockIdx.x, mt = blockIdx.y, z = blockIdx.z;
    const int tid = threadIdx.x;
    const int lane = tid & 63, wid = tid >> 6;
    const int wm = wid >> 2, wn = wid & 3;       // 2(M) x 4(N) waves
    const int lr = lane & 15, kg = lane >> 4;
    const char* wblob = wall + (size_t)z * 2 * PLANE_B;
    char* sblob = sall + (size_t)z * C_DIM * NTOT;
    const float* invz  = invt  + z * C_DIM;
    const float* biasz = biast + z * C_DIM;

    int4v acch[4][2], accl[4][2];
#pragma unroll
    for (int a = 0; a < 4; ++a)
#pragma unroll
        for (int b2 = 0; b2 < 2; ++b2) {
            acch[a][b2] = (int4v){0, 0, 0, 0};
            accl[a][b2] = (int4v){0, 0, 0, 0};
        }

#define STAGE_T(buf, ktArg) do {                                              \
        const char* Ab_ = wblob + (size_t)((ktArg) * MT_N + mt) * TILE_B;     \
        const char* Bb_ = xsblob + (size_t)(jt * KT_N + (ktArg)) * TILE_B;    \
        char* d_ = stage[buf];                                                \
        gload16(Ab_ + (size_t)tid * 16,           d_ + tid * 16);             \
        gload16(Ab_ + PLANE_B + (size_t)tid * 16, d_ + 8192 + tid * 16);      \
        gload16(Bb_ + (size_t)tid * 16,           d_ + 16384 + tid * 16);     \
    } while (0)

    STAGE_T(0, 0);
    __syncthreads();
    int cur = 0;
    const int aoff0 = kg * 2048 + (wm * 64 + lr) * 16;
    const int boff0 = 16384 + kg * 2048 + (wn * 32 + lr) * 16;
    for (int kt = 0; kt < KT_N; ++kt) {
        if (kt + 1 < KT_N) STAGE_T(cur ^ 1, kt + 1);
        const char* st = stage[cur];
        int4v bfr[2];
#pragma unroll
        for (int fn = 0; fn < 2; ++fn)
            bfr[fn] = *(const int4v*)&st[boff0 + fn * 256];
#pragma unroll
        for (int fm = 0; fm < 4; ++fm) {
            int4v ah = *(const int4v*)&st[aoff0 + fm * 256];
            int4v al = *(const int4v*)&st[8192 + aoff0 + fm * 256];
#pragma unroll
            for (int fn = 0; fn < 2; ++fn) {
                acch[fm][fn] = __builtin_amdgcn_mfma_i32_16x16x64_i8(ah, bfr[fn], acch[fm][fn], 0, 0, 0);
                accl[fm][fn] = __builtin_amdgcn_mfma_i32_16x16x64_i8(al, bfr[fn], accl[fm][fn], 0, 0, 0);
            }
        }
        __syncthreads();   // drains next-tile stage (hidden under MFMA above)
        cur ^= 1;
    }

    // ---- epilogue: BN + spike + band records, via LDS u8 tile [128][132]
    unsigned char* sm = (unsigned char*)stage;
#pragma unroll
    for (int fm = 0; fm < 4; ++fm)
#pragma unroll
        for (int fn = 0; fn < 2; ++fn)
#pragma unroll
            for (int r = 0; r < 4; ++r) {
                int ml = wm * 64 + fm * 16 + kg * 4 + r;
                int nl = wn * 32 + fn * 16 + lr;
                int o = mt * 128 + ml;
                int vi = acch[fm][fn][r] * 256 + accl[fm][fn][r];
                float y = (float)vi * 6.103515625e-05f;    // *2^-14, exact
                float ybn = y * invz[o] + biasz[o];
                sm[ml * 132 + nl] = (ybn >= 2.0f) ? 1 : 0;
                if (fabsf(ybn - 2.0f) < TAU) {
                    unsigned int idx = atomicAdd(cnt, 1u);
                    if (idx < CAP_REC) {
                        int j = jt * 128 + nl;
                        recs[idx] = ((unsigned)z << 24) | ((unsigned)o << 14) | (unsigned)j;
                    }
                }
            }
    __syncthreads();
    // ---- write spike blob (i8 B-operand layout), k-tiles kt2 = mt*2+{0,1}
#pragma unroll
    for (int i = 0; i < 2; ++i) {
        int q = tid + i * 512;                    // 0..1023: (kti(2), kg2(4), col(128))
        int kti = q >> 9, rem = q & 511;
        int kg2 = rem >> 7, col = rem & 127;
        char16v vblk;
#pragma unroll
        for (int e = 0; e < 16; ++e)
            vblk[e] = sm[(kti * 64 + kg2 * 16 + e) * 132 + col] ? (char)1 : (char)0;
        *(char16v*)(sblob + (size_t)(jt * KT_N + mt * 2 + kti) * TILE_B + (size_t)rem * 16) = vblk;
    }
}

// ---------------------------------------------------------------------------
// Pass-2 fixup, wave-per-record: bit-exact numpy fp32 re-resolution.
// Only active-spike weights matter (s+0.0f == s); ordered ballot-compaction
// into LDS, lane 0 runs the short strict-order chain.
// ---------------------------------------------------------------------------
__global__ __launch_bounds__(256) void fixup(
    const char* __restrict__ xs,
    const float* __restrict__ wq, const float* __restrict__ wk, const float* __restrict__ wv,
    const float* __restrict__ qg, const float* __restrict__ qb, const float* __restrict__ qm, const float* __restrict__ qv,
    const float* __restrict__ kg, const float* __restrict__ kb2, const float* __restrict__ km, const float* __restrict__ kvr,
    const float* __restrict__ vg, const float* __restrict__ vb, const float* __restrict__ vm, const float* __restrict__ vv,
    char* __restrict__ sq, char* __restrict__ sk, char* __restrict__ sv,
    const unsigned int* __restrict__ cnt, const unsigned int* __restrict__ recs)
{
#pragma clang fp contract(off)
    __shared__ float cw[4][C_DIM];
    const int lane = threadIdx.x & 63;
    const int wvid = threadIdx.x >> 6;
    const int gwave = blockIdx.x * 4 + wvid;
    const int nwaves = gridDim.x * 4;
    unsigned int count = *cnt; if (count > CAP_REC) count = CAP_REC;

    for (unsigned int r = gwave; r < count; r += nwaves) {
        unsigned int rec = recs[r];
        int plane = rec >> 24, o = (rec >> 14) & 1023, j = rec & 16383;
        int jt = j >> 7, col = j & 127;
        const float* w = plane == 0 ? wq : plane == 1 ? wk : wv;
        int base = 0;
#pragma unroll
        for (int cc = 0; cc < 12; ++cc) {
            int c = cc * 64 + lane;
            char s = xs[(size_t)(jt * KT_N + (c >> 6)) * TILE_B
                        + ((c >> 4) & 3) * 2048 + col * 16 + (c & 15)];
            float wvv = w[(size_t)o * C_DIM + c];
            bool act = (s != 0);
            unsigned long long m = __ballot(act);
            int pos = __popcll(m & ((1ull << lane) - 1ull));
            if (act) cw[wvid][base + pos] = wvv;
            base += __popcll(m);
        }
        __builtin_amdgcn_s_waitcnt(0);       // wave-coherent LDS
        if (lane == 0) {
            float s = 0.0f;
            for (int i = 0; i < base; ++i) s = s + cw[wvid][i];   // strict order
            const float* g  = plane == 0 ? qg : plane == 1 ? kg : vg;
            const float* be = plane == 0 ? qb : plane == 1 ? kb2 : vb;
            const float* me = plane == 0 ? qm : plane == 1 ? km : vm;
            const float* va = plane == 0 ? qv : plane == 1 ? kvr : vv;
            float invv = g[o] / sqrtf(va[o] + 1e-5f);
            float t1 = me[o] * invv;
            float bias = be[o] - t1;
            float t3 = s * invv;
            float ybn = t3 + bias;
            char spv = (ybn >= 2.0f) ? (char)1 : (char)0;
            char* blob = plane == 0 ? sq : plane == 1 ? sk : sv;
            blob[(size_t)(jt * KT_N + (o >> 6)) * TILE_B
                 + ((o >> 4) & 3) * 2048 + col * 16 + (o & 15)] = spv;
        }
    }
}

// ---------------------------------------------------------------------------
// maskb[b][c] = OR_n (sk & sv), bytes {0,1}
// ---------------------------------------------------------------------------
__global__ __launch_bounds__(256) void kv_mask_blob(
    const char* __restrict__ sk, const char* __restrict__ sv,
    unsigned char* __restrict__ maskb)
{
    const int kt = blockIdx.x, b = blockIdx.y;
    const int t = threadIdx.x;
    const int kg = t >> 6;
    const int col0 = (t & 63) * 2;
    __shared__ unsigned int lmask[4][4];
    if (t < 16) lmask[t >> 2][t & 3] = 0;
    __syncthreads();
    uint4 acc = make_uint4(0, 0, 0, 0);
    for (int jti = 0; jti < 8; ++jti) {
        size_t base = (size_t)((b * 8 + jti) * KT_N + kt) * TILE_B + kg * 2048;
#pragma unroll
        for (int cc = 0; cc < 2; ++cc) {
            uint4 kk = *(const uint4*)(sk + base + (size_t)(col0 + cc) * 16);
            uint4 vv = *(const uint4*)(sv + base + (size_t)(col0 + cc) * 16);
            acc.x |= (kk.x & vv.x); acc.y |= (kk.y & vv.y);
            acc.z |= (kk.z & vv.z); acc.w |= (kk.w & vv.w);
        }
    }
    if (acc.x) atomicOr(&lmask[kg][0], acc.x);
    if (acc.y) atomicOr(&lmask[kg][1], acc.y);
    if (acc.z) atomicOr(&lmask[kg][2], acc.z);
    if (acc.w) atomicOr(&lmask[kg][3], acc.w);
    __syncthreads();
    if (t < 64) {
        int kg2 = t >> 4, e = t & 15;
        unsigned int dw = lmask[kg2][e >> 2];
        unsigned char byte = (dw >> ((e & 3) * 8)) & 0xFF;
        maskb[(size_t)b * C_DIM + kt * 64 + t] = byte ? 1 : 0;
    }
}

// ---------------------------------------------------------------------------
// Final projection: out = (wp·(sq & mask) + bp)*inv + bias + x
// 512 threads, dbuf 2-phase, mask ANDed into B fragments in registers.
// ---------------------------------------------------------------------------
__global__ __launch_bounds__(512, 4) void final_mfma(
    const char* __restrict__ wblob, const char* __restrict__ sqblob,
    const unsigned char* __restrict__ maskb,
    const float* __restrict__ x, const float* __restrict__ bp,
    const float* __restrict__ invt, const float* __restrict__ biast,
    float* __restrict__ out)
{
    __shared__ char stage[2][24576];
    __shared__ char mlds[768];
    const int jt = blockIdx.x, mt = blockIdx.y;
    const int tid = threadIdx.x;
    const int lane = tid & 63, wid = tid >> 6;
    const int wm = wid >> 2, wn = wid & 3;
    const int lr = lane & 15, kg = lane >> 4;
    const int b = jt >> 3;
    const float* invp  = invt  + 3 * C_DIM;
    const float* biasp = biast + 3 * C_DIM;

    if (tid < 48)
        *(int4v*)&mlds[tid * 16] = *(const int4v*)(maskb + (size_t)b * C_DIM + tid * 16);

    int4v acch[4][2], accl[4][2];
#pragma unroll
    for (int a = 0; a < 4; ++a)
#pragma unroll
        for (int b2 = 0; b2 < 2; ++b2) {
            acch[a][b2] = (int4v){0, 0, 0, 0};
            accl[a][b2] = (int4v){0, 0, 0, 0};
        }

#define STAGE_F(buf, ktArg) do {                                              \
        const char* Ab_ = wblob + (size_t)((ktArg) * MT_N + mt) * TILE_B;     \
        const char* Bb_ = sqblob + (size_t)(jt * KT_N + (ktArg)) * TILE_B;    \
        char* d_ = stage[buf];                                                \
        gload16(Ab_ + (size_t)tid * 16,           d_ + tid * 16);             \
        gload16(Ab_ + PLANE_B + (size_t)tid * 16, d_ + 8192 + tid * 16);      \
        gload16(Bb_ + (size_t)tid * 16,           d_ + 16384 + tid * 16);     \
    } while (0)

    STAGE_F(0, 0);
    __syncthreads();
    int cur = 0;
    const int aoff0 = kg * 2048 + (wm * 64 + lr) * 16;
    const int boff0 = 16384 + kg * 2048 + (wn * 32 + lr) * 16;
    for (int kt = 0; kt < KT_N; ++kt) {
        if (kt + 1 < KT_N) STAGE_F(cur ^ 1, kt + 1);
        const char* st = stage[cur];
        int4v mp = *(const int4v*)&mlds[kt * 64 + kg * 16];
        int4v bfr[2];
#pragma unroll
        for (int fn = 0; fn < 2; ++fn) {
            bfr[fn] = *(const int4v*)&st[boff0 + fn * 256];
            bfr[fn] &= mp;
        }
#pragma unroll
        for (int fm = 0; fm < 4; ++fm) {
            int4v ah = *(const int4v*)&st[aoff0 + fm * 256];
            int4v al = *(const int4v*)&st[8192 + aoff0 + fm * 256];
#pragma unroll
            for (int fn = 0; fn < 2; ++fn) {
                acch[fm][fn] = __builtin_amdgcn_mfma_i32_16x16x64_i8(ah, bfr[fn], acch[fm][fn], 0, 0, 0);
                accl[fm][fn] = __builtin_amdgcn_mfma_i32_16x16x64_i8(al, bfr[fn], accl[fm][fn], 0, 0, 0);
            }
        }
        __syncthreads();
        cur ^= 1;
    }

    const int n0 = (jt & 7) * 128;
#pragma unroll
    for (int fm = 0; fm < 4; ++fm)
#pragma unroll
        for (int fn = 0; fn < 2; ++fn)
#pragma unroll
            for (int r = 0; r < 4; ++r) {
                int ml = wm * 64 + fm * 16 + kg * 4 + r;
                int nl = wn * 32 + fn * 16 + lr;
                int p = mt * 128 + ml;
                int vi = acch[fm][fn][r] * 256 + accl[fm][fn][r];
                float pre = (float)vi * 6.103515625e-05f;
                size_t idx = ((size_t)b * C_DIM + p) * NPIX + n0 + nl;
                out[idx] = (pre + bp[p]) * invp[p] + biasp[p] + x[idx];
            }
}

extern "C" void kernel_launch(void* const* d_in, const int* in_sizes, int n_in,
                              void* d_out, int out_size, void* d_ws, size_t ws_size,
                              hipStream_t stream) {
    const float* x  = (const float*)d_in[0];
    const float* wq = (const float*)d_in[1];
    const float* qg = (const float*)d_in[2];
    const float* qb = (const float*)d_in[3];
    const float* qm = (const float*)d_in[4];
    const float* qv = (const float*)d_in[5];
    const float* wk = (const float*)d_in[6];
    const float* kg = (const float*)d_in[7];
    const float* kb = (const float*)d_in[8];
    const float* km = (const float*)d_in[9];
    const float* kvv= (const float*)d_in[10];
    const float* wv = (const float*)d_in[11];
    const float* vg = (const float*)d_in[12];
    const float* vb = (const float*)d_in[13];
    const float* vm = (const float*)d_in[14];
    const float* vv = (const float*)d_in[15];
    const float* wp = (const float*)d_in[16];
    const float* bp = (const float*)d_in[17];
    const float* pg = (const float*)d_in[18];
    const float* pb = (const float*)d_in[19];
    const float* pm = (const float*)d_in[20];
    const float* pv = (const float*)d_in[21];

    const size_t SPIKE = (size_t)C_DIM * NTOT;       // bytes per spike blob
    char* sq  = (char*)d_ws;
    char* sk  = sq + SPIKE;
    char* sv  = sk + SPIKE;
    char* xs  = sv + SPIKE;
    char* wall = xs + SPIKE;                         // 4 sets x 2 planes
    unsigned char* maskb = (unsigned char*)(wall + (size_t)4 * 2 * PLANE_B);
    unsigned int* cnt  = (unsigned int*)(maskb + 16384);
    unsigned int* recs = (unsigned int*)((char*)cnt + 256);
    float* invt  = (float*)((char*)recs + CAP_REC * 4);
    float* biast = invt + 4 * C_DIM;
    char* wpb = wall + (size_t)3 * 2 * PLANE_B;

    hipMemsetAsync(cnt, 0, 4, stream);
    prep_weights<<<dim3(KT_N * MT_N, 4), 256, 0, stream>>>(wq, wk, wv, wp, wall);
    prep_bn<<<12, 256, 0, stream>>>(qg, qb, qm, qv, kg, kb, km, kvv,
                                    vg, vb, vm, vv, pg, pb, pm, pv, invt, biast);
    prep_spikes<<<dim3(JT_N, KT_N), 256, 0, stream>>>(x, xs);
    branch_mfma<<<dim3(JT_N, MT_N, 3), 512, 0, stream>>>(
        wall, xs, invt, biast, sq, cnt, recs);
    fixup<<<2048, 256, 0, stream>>>(xs, wq, wk, wv,
                                    qg, qb, qm, qv, kg, kb, km, kvv, vg, vb, vm, vv,
                                    sq, sk, sv, cnt, recs);
    kv_mask_blob<<<dim3(KT_N, B_DIM), 256, 0, stream>>>(sk, sv, maskb);
    final_mfma<<<dim3(JT_N, MT_N), 512, 0, stream>>>(
        wpb, sq, maskb, x, bp, invt, biast, (float*)d_out);
}